// Round 7
// baseline (1016.783 us; speedup 1.0000x reference)
//
#include <hip/hip_runtime.h>
#include <hip/hip_fp16.h>
#include <math.h>

#define BB 32
#define NN 128
#define CC 16
#define OO 32
#define II 32
#define JJ 32
#define MM (NN*CC)

// One block per (b,o), 512 threads. NO u_hat anywhere (R3-R6 all spilled trying
// to persist it): routing is factored through cx/wv, which cuts FLOPs 4x:
//   phase A: cx[c,i] = sum_n cf[c,n]*x[n,c,i]        (butterfly over 32 lanes)
//            s[j]    = sum_{c,i} cx[c,i]*W[c,o,i,j]  (butterfly + LDS fold)
//   phase B: wv[c,i] = sum_j W[c,o,i,j]*v[j]
//            b_ij[c,n] += sum_i x[n,c,i]*wv[c,i]
// Persistent state: 4 x-rows fp16-packed (xh[4][16] = 64 VGPRs) + bv[4].
// Peak live ~105 (xh64 + p32 + temps) < the 128 the allocator grants at
// 512thr/__launch_bounds__(512,2) (R3/R6 evidence) -> no spill. W is never
// persisted (8 transient float4, L1-hot). LDS ~6.5 KB -> 2 blocks/CU.
__global__ __launch_bounds__(512, 2) void k_caps(
    const float* __restrict__ x, const float* __restrict__ W,
    float* __restrict__ out) {
  __shared__ float cxs[512];        // cx[c][i]
  __shared__ float wvs[512];        // wv[c][i]
  __shared__ float swred[8][32];    // per-wave s[j] partials
  __shared__ float vj[32];          // squashed capsule
  __shared__ float red1[8], red2[8];

  int bid = blockIdx.x;
  int b = ((bid & 7) << 2) | ((bid >> 3) & 3);  // XCD-affinity: same-b -> same XCD L2
  int o = bid >> 5;
  int tid = threadIdx.x;
  int lane = tid & 63, wave = tid >> 6;
  int nn = tid & 31;
  int c  = tid >> 5;                // 0..15; my 4 rows n = nn + 32r share this c

  // ---- load my 4 x rows, pack fp16 (rel err 5e-4; R6 measured 5e-3 absmax
  //      with the same class of rounding vs 2e-2 threshold) ----
  __half2 xh[4][16];
  #pragma unroll
  for (int r = 0; r < 4; ++r) {
    const float* xp = x + ((size_t)(b * NN + (nn + 32 * r)) * CC + c) * II;
    #pragma unroll
    for (int q = 0; q < 8; ++q) {
      float4 x4 = *(const float4*)(xp + 4 * q);
      xh[r][2*q]   = __float22half2_rn(make_float2(x4.x, x4.y));
      xh[r][2*q+1] = __float22half2_rn(make_float2(x4.z, x4.w));
    }
  }

  const float* wrow = W + ((size_t)(c * OO + o) * II + nn) * JJ;  // W[c,o,i=nn,:]

  float bv[4] = {0.f, 0.f, 0.f, 0.f};  // my 4 b_ij entries
  float mx = 0.f;
  float rinv = 1.0f / (float)MM;       // softmax(0) == uniform 1/2048

  for (int t = 0; t < 3; ++t) {
    // ---- phase A: p[i] = sum_r cf[r]*x[r][i]; butterfly -> cx[c][i] ----
    float p[32];
    #pragma unroll
    for (int i = 0; i < 32; ++i) p[i] = 0.f;
    #pragma unroll
    for (int r = 0; r < 4; ++r) {
      float cf = __expf(bv[r] - mx) * rinv;
      #pragma unroll
      for (int q = 0; q < 16; ++q) {
        float2 xx = __half22float2(xh[r][q]);
        p[2*q]   = fmaf(cf, xx.x, p[2*q]);
        p[2*q+1] = fmaf(cf, xx.y, p[2*q+1]);
      }
    }
    // vector-halving butterfly within each 32-lane group (lane nn ends w/ elem nn)
    #pragma unroll
    for (int h = 16; h >= 1; h >>= 1) {
      bool hi = (nn & h) != 0;
      #pragma unroll
      for (int e = 0; e < 16; ++e) {
        if (e < h) {
          float send = hi ? p[e] : p[e + h];
          float keep = hi ? p[e + h] : p[e];
          p[e] = keep + __shfl_xor(send, h);
        }
      }
    }
    cxs[tid] = p[0];                 // cx[c][i=nn]; NO cross-c fold here
    __syncthreads();

    // ---- s[j] = sum_{c,i} cx[c,i]*W[c,o,i,j]: per-thread vector over j,
    //      butterfly over i (32 lanes), fold the wave's 2 c's, LDS-fold 8 waves
    float cxv = cxs[tid];
    float sp[32];
    #pragma unroll
    for (int q = 0; q < 8; ++q) {
      float4 w4 = *(const float4*)(wrow + 4 * q);
      sp[4*q+0] = cxv * w4.x;
      sp[4*q+1] = cxv * w4.y;
      sp[4*q+2] = cxv * w4.z;
      sp[4*q+3] = cxv * w4.w;
    }
    #pragma unroll
    for (int h = 16; h >= 1; h >>= 1) {
      bool hi = (nn & h) != 0;
      #pragma unroll
      for (int e = 0; e < 16; ++e) {
        if (e < h) {
          float send = hi ? sp[e] : sp[e + h];
          float keep = hi ? sp[e + h] : sp[e];
          sp[e] = keep + __shfl_xor(send, h);
        }
      }
    }
    float sv = sp[0] + __shfl_xor(sp[0], 32);   // fold the wave's two c's
    if (lane < 32) swred[wave][lane] = sv;
    __syncthreads();

    // ---- squash on 32 threads ----
    if (tid < 32) {
      float s = 0.f;
      #pragma unroll
      for (int w = 0; w < 8; ++w) s += swred[w][tid];
      float msq = s * s;
      #pragma unroll
      for (int off = 16; off > 0; off >>= 1) msq += __shfl_xor(msq, off);
      float mag = sqrtf(msq) + 1e-11f;
      float a = msq / (1.0f + msq);
      float vv = a * s / mag;
      vj[tid] = vv;
      if (t == 2) {
        out[((size_t)b * OO + o) * JJ + tid] = vv;        // v_j [B,1,O,J]
        if (tid == 0) out[BB * OO * JJ + b * OO + o] = a; // a_j [B,1,O,1]
      }
    }
    __syncthreads();
    if (t == 2) break;   // reference discards the last b_ij update

    // ---- phase B: wv[c,i] = dot(W[c,o,i,:], v) ----
    float wvacc = 0.f;
    #pragma unroll
    for (int q = 0; q < 8; ++q) {
      float4 w4 = *(const float4*)(wrow + 4 * q);   // L1-hot (2nd visit this iter)
      float4 v4 = *(const float4*)&vj[4 * q];       // LDS broadcast
      wvacc = fmaf(w4.x, v4.x, wvacc);
      wvacc = fmaf(w4.y, v4.y, wvacc);
      wvacc = fmaf(w4.z, v4.z, wvacc);
      wvacc = fmaf(w4.w, v4.w, wvacc);
    }
    wvs[tid] = wvacc;
    __syncthreads();

    // ---- u.v rows: bv[r] += sum_i x[r][i]*wv[c][i]; then block softmax stats
    float wr[32];
    #pragma unroll
    for (int q = 0; q < 8; ++q) {
      float4 w4 = *(const float4*)&wvs[c * 32 + 4 * q];  // broadcast within group
      wr[4*q+0] = w4.x; wr[4*q+1] = w4.y; wr[4*q+2] = w4.z; wr[4*q+3] = w4.w;
    }
    #pragma unroll
    for (int r = 0; r < 4; ++r) {
      float d = 0.f;
      #pragma unroll
      for (int q = 0; q < 16; ++q) {
        float2 xx = __half22float2(xh[r][q]);
        d = fmaf(xx.x, wr[2*q],   d);
        d = fmaf(xx.y, wr[2*q+1], d);
      }
      bv[r] += d;
    }

    float m_ = fmaxf(fmaxf(bv[0], bv[1]), fmaxf(bv[2], bv[3]));
    #pragma unroll
    for (int off = 32; off > 0; off >>= 1) m_ = fmaxf(m_, __shfl_xor(m_, off));
    if (lane == 0) red1[wave] = m_;
    __syncthreads();
    mx = fmaxf(fmaxf(fmaxf(red1[0], red1[1]), fmaxf(red1[2], red1[3])),
               fmaxf(fmaxf(red1[4], red1[5]), fmaxf(red1[6], red1[7])));

    float sx = (__expf(bv[0] - mx) + __expf(bv[1] - mx)) +
               (__expf(bv[2] - mx) + __expf(bv[3] - mx));
    #pragma unroll
    for (int off = 32; off > 0; off >>= 1) sx += __shfl_xor(sx, off);
    if (lane == 0) red2[wave] = sx;
    __syncthreads();
    rinv = 1.0f / (((red2[0] + red2[1]) + (red2[2] + red2[3])) +
                   ((red2[4] + red2[5]) + (red2[6] + red2[7])));
    __syncthreads();   // protect red1/red2/swred/cxs reuse next iteration
  }
}

extern "C" void kernel_launch(void* const* d_in, const int* in_sizes, int n_in,
                              void* d_out, int out_size, void* d_ws, size_t ws_size,
                              hipStream_t stream) {
  const float* x = (const float*)d_in[0];   // [B,N,C,I] fp32
  const float* W = (const float*)d_in[1];   // [C,O,I,J] fp32
  (void)in_sizes; (void)n_in; (void)d_ws; (void)ws_size; (void)out_size;
  float* out = (float*)d_out;               // v_j (32768) ++ a_j (1024)
  k_caps<<<BB * OO, 512, 0, stream>>>(x, W, out);
}